// Round 6
// baseline (135.905 us; speedup 1.0000x reference)
//
#include <hip/hip_runtime.h>

// Single-scale fixed-size deformable attention.
// value:  (BS, H*W, NH, HD) f32
// sloc:   (BS, NQ, NH, 1, NP, 2) f32  (locations in [0,1])
// aw:     (BS, NQ, NH, 1, NP) f32
// out:    (BS, NQ, NH*HD) f32
//
// R4: 68.7us, FETCH 226MB. R5 (+XCD slab swizzle): 51.5us, FETCH 54.7MB
// (compulsory), VALU 27%, BW 23% -> latency/request-rate bound.
// R6: 2 groups/thread (2x wave MLP) + octet reorder (wave = 8lane x 4h x 2q:
// param loads 2 lines/instr instead of 8, stores 512B-contiguous).

constexpr int BS = 4, NQ = 10000, NH = 8, HD = 32, NP = 4, H = 100, W = 100;
constexpr int HW = H * W;
constexpr int NQH = NQ / 2;                     // 5000: second group at q + NQH

typedef float f32x4 __attribute__((ext_vector_type(4)));

__device__ __forceinline__ void bilinear_accum(const float lx[NP], const float ly[NP],
                                               const float wp[NP],
                                               const float* __restrict__ vbase,
                                               f32x4& acc)
{
#pragma unroll
    for (int p = 0; p < NP; ++p) {
        const float x = lx[p] * (float)W - 0.5f;
        const float y = ly[p] * (float)H - 0.5f;
        const float x0f = floorf(x);
        const float y0f = floorf(y);
        const int   x0  = (int)x0f, y0 = (int)y0f;
        const int   x1  = x0 + 1,   y1 = y0 + 1;
        const float wx1 = x - x0f,  wx0 = 1.f - wx1;
        const float wy1 = y - y0f,  wy0 = 1.f - wy1;

        const bool vx0 = (unsigned)x0 < (unsigned)W;
        const bool vx1 = (unsigned)x1 < (unsigned)W;
        const bool vy0 = (unsigned)y0 < (unsigned)H;
        const bool vy1 = (unsigned)y1 < (unsigned)H;

        const int xc0 = min(max(x0, 0), W - 1);
        const int xc1 = min(max(x1, 0), W - 1);
        const int yc0 = min(max(y0, 0), H - 1);
        const int yc1 = min(max(y1, 0), H - 1);

        // zeros padding: invalid corner -> weight 0 (load stays in-bounds via clamp)
        const float w00 = (vx0 && vy0) ? wp[p] * wx0 * wy0 : 0.f;
        const float w10 = (vx1 && vy0) ? wp[p] * wx1 * wy0 : 0.f;
        const float w01 = (vx0 && vy1) ? wp[p] * wx0 * wy1 : 0.f;
        const float w11 = (vx1 && vy1) ? wp[p] * wx1 * wy1 : 0.f;

        const f32x4 v00 = *(const f32x4*)(vbase + (size_t)(yc0 * W + xc0) * (NH * HD));
        const f32x4 v10 = *(const f32x4*)(vbase + (size_t)(yc0 * W + xc1) * (NH * HD));
        const f32x4 v01 = *(const f32x4*)(vbase + (size_t)(yc1 * W + xc0) * (NH * HD));
        const f32x4 v11 = *(const f32x4*)(vbase + (size_t)(yc1 * W + xc1) * (NH * HD));

        acc += w00 * v00 + w10 * v10 + w01 * v01 + w11 * v11;
    }
}

__global__ __launch_bounds__(256)
void deform_attn_kernel(const float* __restrict__ value,
                        const float* __restrict__ sloc,
                        const float* __restrict__ aw,
                        float* __restrict__ out)
{
    // grid = 5000 blocks. Default dispatch: XCD = blockIdx % 8, so quad
    // (= 4 consecutive (b,h) slabs, 4x1.28MB < 4MB L2) pins to one XCD.
    const int quad = blockIdx.x & 7;            // which (b, h-quad)
    const int c    = blockIdx.x >> 3;           // [0, 625) within quad

    const int t    = threadIdx.x;
    const int lane = t & 7;                     // channel quad (16B)
    const int h_i  = (t >> 3) & 3;              // h within quad
    const int slot = t >> 5;                    // q slot [0, 8)

    const int b = quad >> 1;
    const int h = ((quad & 1) << 2) + h_i;
    const int q = (c << 3) + slot;              // [0, 5000)

    const int bq1 = b * NQ + q;                 // group 1: (b, q, h)
    const int bq2 = bq1 + NQH;                  // group 2: (b, q+5000, h)

    // Params for both groups up front -> 6 independent loads in flight.
    const size_t p1 = (size_t)bq1 * NH + h;
    const size_t p2 = (size_t)bq2 * NH + h;
    const f32x4 a01 = *(const f32x4*)(sloc + p1 * (NP * 2));
    const f32x4 a23 = *(const f32x4*)(sloc + p1 * (NP * 2) + 4);
    const f32x4 awa = *(const f32x4*)(aw   + p1 * NP);
    const f32x4 b01 = *(const f32x4*)(sloc + p2 * (NP * 2));
    const f32x4 b23 = *(const f32x4*)(sloc + p2 * (NP * 2) + 4);
    const f32x4 awb = *(const f32x4*)(aw   + p2 * NP);

    const float lxa[NP] = {a01.x, a01.z, a23.x, a23.z};
    const float lya[NP] = {a01.y, a01.w, a23.y, a23.w};
    const float wpa[NP] = {awa.x, awa.y, awa.z, awa.w};
    const float lxb[NP] = {b01.x, b01.z, b23.x, b23.z};
    const float lyb[NP] = {b01.y, b01.w, b23.y, b23.w};
    const float wpb[NP] = {awb.x, awb.y, awb.z, awb.w};

    const float* vbase = value + (size_t)b * HW * NH * HD + h * HD + lane * 4;

    f32x4 acc1 = (f32x4)(0.f);
    f32x4 acc2 = (f32x4)(0.f);
    bilinear_accum(lxa, lya, wpa, vbase, acc1);
    bilinear_accum(lxb, lyb, wpb, vbase, acc2);

    // Stores: within a wave, 4h x 8 channel-lanes = 512B contiguous per q-slot.
    __builtin_nontemporal_store(acc1, (f32x4*)(out + (size_t)bq1 * (NH * HD) + h * HD + lane * 4));
    __builtin_nontemporal_store(acc2, (f32x4*)(out + (size_t)bq2 * (NH * HD) + h * HD + lane * 4));
}

extern "C" void kernel_launch(void* const* d_in, const int* in_sizes, int n_in,
                              void* d_out, int out_size, void* d_ws, size_t ws_size,
                              hipStream_t stream) {
    const float* value = (const float*)d_in[0];
    // d_in[1] = value_spatial_shapes (int64) — unused in fixed-size variant
    const float* sloc  = (const float*)d_in[2];
    const float* aw    = (const float*)d_in[3];
    float*       out   = (float*)d_out;

    // 5000 blocks x 256 threads x 2 groups/thread = 2,560,000 groups*lanes
    deform_attn_kernel<<<5000, 256, 0, stream>>>(value, sloc, aw, out);
}